// Round 5
// baseline (677.401 us; speedup 1.0000x reference)
//
#include <hip/hip_runtime.h>
#include <math.h>

constexpr int B_ = 8;
constexpr int N_ = 1024;
constexpr int K_ = 20;
constexpr float EPS_ = 1e-5f;

typedef __attribute__((ext_vector_type(8))) short short8;
typedef __attribute__((ext_vector_type(4))) float f32x4;
typedef unsigned long long u64;

// hi/lo bf16 split (RNE both halves)
__device__ __forceinline__ void bf16split(float x, unsigned short& h, unsigned short& l) {
    unsigned u = __float_as_uint(x);
    unsigned rh = (u + 0x7FFFu + ((u >> 16) & 1u)) >> 16;
    h = (unsigned short)rh;
    float lof = x - __uint_as_float(rh << 16);
    unsigned ul = __float_as_uint(lof);
    l = (unsigned short)((ul + 0x7FFFu + ((ul >> 16) & 1u)) >> 16);
}

// ---------------------------------------------------------------- split + sq
// h (B*N, C) fp32 -> Hh/Hl (B*N, CP) bf16 hi/lo (zero-padded), sq fp32.
template <int C, int CP>
__global__ __launch_bounds__(256) void split_kernel(const float* __restrict__ h,
                                                    unsigned short* __restrict__ Hh,
                                                    unsigned short* __restrict__ Hl,
                                                    float* __restrict__ sq) {
    int p = blockIdx.x * 256 + threadIdx.x;
    if (p >= B_ * N_) return;
    const float* r = h + (size_t)p * C;
    unsigned short hb[CP], lb[CP];
    float s = 0.f;
#pragma unroll
    for (int c = 0; c < C; ++c) {
        float v = r[c];
        s += v * v;
        bf16split(v, hb[c], lb[c]);
    }
#pragma unroll
    for (int c = C; c < CP; ++c) { hb[c] = 0; lb[c] = 0; }
    sq[p] = s;
#pragma unroll
    for (int i = 0; i < CP / 8; ++i) {
        *(short8*)&Hh[(size_t)p * CP + 8 * i] = *(const short8*)&hb[8 * i];
        *(short8*)&Hl[(size_t)p * CP + 8 * i] = *(const short8*)&lb[8 * i];
    }
}

// ---------------------------------------------------------------- knn kernel
__device__ __forceinline__ unsigned int fkey(float f) {
    unsigned int u = __float_as_uint(f);
    return (u & 0x80000000u) ? ~u : (u | 0x80000000u);
}

__device__ __forceinline__ u64 tree16(const u64* v) {
    u64 t0[8];
#pragma unroll
    for (int s = 0; s < 8; ++s) t0[s] = v[2 * s] > v[2 * s + 1] ? v[2 * s] : v[2 * s + 1];
#pragma unroll
    for (int s = 0; s < 4; ++s) t0[s] = t0[2 * s] > t0[2 * s + 1] ? t0[2 * s] : t0[2 * s + 1];
    t0[0] = t0[0] > t0[1] ? t0[0] : t0[1];
    t0[2] = t0[2] > t0[3] ? t0[2] : t0[3];
    return t0[0] > t0[2] ? t0[0] : t0[2];
}

// Phase A: MFMA distance (8 rows x 1024 cols per block, wave covers 256 cols),
// split-bf16 from pre-split Hh/Hl (row-major -> B fragment needs no transpose).
// Phase B: per-wave 2-row interleaved top-20 selection (u64 keys).
template <int CP>
__global__ __launch_bounds__(256) void knn_kernel(const unsigned short* __restrict__ Hh,
                                                  const unsigned short* __restrict__ Hl,
                                                  const float* __restrict__ sq,
                                                  int* __restrict__ idx) {
    constexpr int ROWS = 8;
    constexpr int KC = CP / 32;
    __shared__ float dist[ROWS][1028];  // +4 pad: MFMA-store & phaseB reads <=2-way banks
    int t = threadIdx.x;
    int bb = blockIdx.x / (N_ / ROWS);
    int r0 = (blockIdx.x % (N_ / ROWS)) * ROWS;
    int lane = t & 63, wave = t >> 6, quad = lane >> 4, nl = lane & 15;
    size_t base = (size_t)bb * N_;
    int n0w = wave * 256;

    f32x4 acc[16];
#pragma unroll
    for (int nt = 0; nt < 16; ++nt) acc[nt] = (f32x4){0.f, 0.f, 0.f, 0.f};

    const short8 zero = {0, 0, 0, 0, 0, 0, 0, 0};
#pragma unroll
    for (int kc = 0; kc < KC; ++kc) {
        // A fragment: rows r0..r0+7 (m 8..15 zero).  A[m=nl][k=quad*8+j]
        size_t ar = (base + r0 + (nl & 7)) * CP + kc * 32 + quad * 8;
        short8 ah = *(const short8*)&Hh[ar];
        short8 al = *(const short8*)&Hl[ar];
        ah = (nl < 8) ? ah : zero;
        al = (nl < 8) ? al : zero;
#pragma unroll
        for (int nt = 0; nt < 16; ++nt) {
            // B fragment: B[k=quad*8+j][n=nl] = X[col][k] -> contiguous dwordx4
            size_t br = (base + n0w + nt * 16 + nl) * CP + kc * 32 + quad * 8;
            short8 bh = *(const short8*)&Hh[br];
            short8 bl = *(const short8*)&Hl[br];
            acc[nt] = __builtin_amdgcn_mfma_f32_16x16x32_bf16(ah, bh, acc[nt], 0, 0, 0);
            acc[nt] = __builtin_amdgcn_mfma_f32_16x16x32_bf16(ah, bl, acc[nt], 0, 0, 0);
            acc[nt] = __builtin_amdgcn_mfma_f32_16x16x32_bf16(al, bh, acc[nt], 0, 0, 0);
        }
    }

    // epilogue: d = 2*dot - sq_row - sq_col, store rows 0..7 (quads 0,1)
    float sqm[4];
#pragma unroll
    for (int r = 0; r < 4; ++r) sqm[r] = sq[base + r0 + ((quad * 4 + r) & 7)];
#pragma unroll
    for (int nt = 0; nt < 16; ++nt) {
        float sqn = sq[base + n0w + nt * 16 + nl];
        if (quad < 2) {
#pragma unroll
            for (int r = 0; r < 4; ++r)
                dist[quad * 4 + r][n0w + nt * 16 + nl] = 2.f * acc[nt][r] - sqm[r] - sqn;
        }
    }
    __syncthreads();

    // ---- phase B: wave w selects top-20 for rows 2w, 2w+1 (interleaved chains)
    int row0 = 2 * wave, row1 = 2 * wave + 1;
    u64 v0[16], v1[16];
#pragma unroll
    for (int j = 0; j < 16; ++j) {
        int c = lane + 64 * j;
        v0[j] = ((u64)fkey(dist[row0][c]) << 32) | (unsigned int)(~c);
        v1[j] = ((u64)fkey(dist[row1][c]) << 32) | (unsigned int)(~c);
    }
    int* op0 = idx + (size_t)(base + r0 + row0) * K_;
    int* op1 = idx + (size_t)(base + r0 + row1) * K_;

    for (int it = 0; it < K_; ++it) {
        u64 m0 = tree16(v0);
        u64 m1 = tree16(v1);
#pragma unroll
        for (int off = 32; off; off >>= 1) {
            u64 o0 = __shfl_xor(m0, off);
            u64 o1 = __shfl_xor(m1, off);
            m0 = o0 > m0 ? o0 : m0;
            m1 = o1 > m1 ? o1 : m1;
        }
        if (lane == 0) {
            op0[it] = (int)(~(unsigned int)m0);
            op1[it] = (int)(~(unsigned int)m1);
        }
#pragma unroll
        for (int j = 0; j < 16; ++j) {
            v0[j] = (v0[j] == m0) ? 0ull : v0[j];
            v1[j] = (v1[j] == m1) ? 0ull : v1[j];
        }
    }
}

// ---------------------------------------------------------------- fp32 weight prep (L1)
template <int CIN, int COUT>
__global__ __launch_bounds__(256) void prep_kernel(const float* __restrict__ w,
                                                   const float* __restrict__ g,
                                                   const float* __restrict__ bb,
                                                   const float* __restrict__ m,
                                                   const float* __restrict__ v,
                                                   float* __restrict__ wdT,
                                                   float* __restrict__ wcdT,
                                                   float* __restrict__ bias2) {
    int e = blockIdx.x * 256 + threadIdx.x;
    if (e >= CIN * COUT) return;
    int o = e % COUT;
    int i = e / COUT;
    float a = g[o] / sqrtf(v[o] + EPS_);
    float wd = w[o * 2 * CIN + i];
    wdT[e] = a * wd;
    wcdT[e] = a * (w[o * 2 * CIN + CIN + i] - wd);
    if (i == 0) bias2[o] = bb[o] - m[o] * a;
}

// ---------------------------------------------------------------- MFMA weight prep
template <int CIN, int COUT>
__global__ __launch_bounds__(256) void prep_mfma(const float* __restrict__ w,
                                                 const float* __restrict__ g,
                                                 const float* __restrict__ bb,
                                                 const float* __restrict__ m,
                                                 const float* __restrict__ v,
                                                 unsigned short* __restrict__ Wh,
                                                 unsigned short* __restrict__ Wl,
                                                 float* __restrict__ wcdT,
                                                 float* __restrict__ bias2) {
    int e = blockIdx.x * 256 + threadIdx.x;
    if (e >= CIN * COUT) return;
    int n = e % COUT, k = e / COUT;
    float a = g[n] / sqrtf(v[n] + EPS_);
    float wdv = a * w[n * 2 * CIN + k];
    unsigned short h, l;
    bf16split(wdv, h, l);
    int kc = k >> 5, ko = k & 31, quad = ko >> 3, j = ko & 7;
    int nt = n >> 4, nl = n & 15;
    constexpr int NT = COUT / 16;
    size_t pos = ((size_t)(kc * NT + nt) * 64 + quad * 16 + nl) * 8 + j;
    Wh[pos] = h;
    Wl[pos] = l;
    wcdT[k * COUT + n] = a * (w[n * 2 * CIN + CIN + k] - w[n * 2 * CIN + k]);
    if (k == 0) bias2[n] = bb[n] - m[n] * a;
}

// ---------------------------------------------------------------- ctr-term (fp32)
template <int CIN, int COUT, int PP>
__global__ __launch_bounds__(COUT) void cterm_kernel(const float* __restrict__ x,
                                                     const float* __restrict__ wcdT,
                                                     const float* __restrict__ bias2,
                                                     float* __restrict__ ct) {
    __shared__ float ctr[PP][CIN];
    int p0 = blockIdx.x * PP;
    int t = threadIdx.x;
    for (int e = t; e < PP * CIN; e += COUT)
        ctr[e / CIN][e % CIN] = x[(size_t)p0 * CIN + e];
    __syncthreads();
    float acc[PP];
#pragma unroll
    for (int pp = 0; pp < PP; ++pp) acc[pp] = bias2[t];
    for (int i = 0; i < CIN; ++i) {
        float w = wcdT[i * COUT + t];
#pragma unroll
        for (int pp = 0; pp < PP; ++pp) acc[pp] = fmaf(w, ctr[pp][i], acc[pp]);
    }
#pragma unroll
    for (int pp = 0; pp < PP; ++pp) ct[(size_t)(p0 + pp) * COUT + t] = acc[pp];
}

// ---------------------------------------------------------------- MFMA edge conv
// Staging now reads pre-split Hh/Hl (no per-block bf16split, half the loads).
template <int CIN, int COUT, int P>
__global__ __launch_bounds__(256) void convm_kernel(const unsigned short* __restrict__ Hh,
                                                    const unsigned short* __restrict__ Hl,
                                                    const int* __restrict__ idx,
                                                    const unsigned short* __restrict__ Wh,
                                                    const unsigned short* __restrict__ Wl,
                                                    const float* __restrict__ cterm,
                                                    float* __restrict__ out) {
    constexpr int ROWS = P * K_;
    constexpr int MT = ROWS / 16;
    constexpr int NT = COUT / 16;
    constexpr int NTW = NT / 4;
    constexpr int KC = CIN / 32;
    constexpr int STR = CIN + 8;
    __shared__ unsigned short Ahi[ROWS * STR];
    __shared__ unsigned short Alo[ROWS * STR];
    __shared__ int nidx[ROWS];

    int t = threadIdx.x;
    int bb = blockIdx.x / (N_ / P);
    int p0 = (blockIdx.x % (N_ / P)) * P;

    if (t < ROWS) nidx[t] = idx[((size_t)(bb * N_ + p0 + t / K_)) * K_ + t % K_];
    __syncthreads();

    constexpr int CH8 = ROWS * (CIN / 8);
    for (int c = t; c < CH8; c += 256) {
        int r = c / (CIN / 8), cc = c % (CIN / 8);
        size_t src = ((size_t)(bb * N_ + nidx[r])) * CIN + 8 * cc;
        *(short8*)&Ahi[r * STR + 8 * cc] = *(const short8*)&Hh[src];
        *(short8*)&Alo[r * STR + 8 * cc] = *(const short8*)&Hl[src];
    }
    __syncthreads();

    int lane = t & 63, wave = t >> 6, quad = lane >> 4, nl = lane & 15;

    f32x4 acc[MT][NTW];
#pragma unroll
    for (int mt = 0; mt < MT; ++mt)
#pragma unroll
        for (int n = 0; n < NTW; ++n) acc[mt][n] = (f32x4){0.f, 0.f, 0.f, 0.f};

#pragma unroll
    for (int kc = 0; kc < KC; ++kc) {
        short8 ah[MT], al[MT];
#pragma unroll
        for (int mt = 0; mt < MT; ++mt) {
            int off = (mt * 16 + nl) * STR + kc * 32 + quad * 8;
            ah[mt] = *(const short8*)&Ahi[off];
            al[mt] = *(const short8*)&Alo[off];
        }
#pragma unroll
        for (int ntw = 0; ntw < NTW; ++ntw) {
            int ntg = wave * NTW + ntw;
            const short8 bh = *(const short8*)&Wh[((size_t)(kc * NT + ntg) * 64 + lane) * 8];
            const short8 bl = *(const short8*)&Wl[((size_t)(kc * NT + ntg) * 64 + lane) * 8];
#pragma unroll
            for (int mt = 0; mt < MT; ++mt) {
                acc[mt][ntw] = __builtin_amdgcn_mfma_f32_16x16x32_bf16(ah[mt], bh, acc[mt][ntw], 0, 0, 0);
                acc[mt][ntw] = __builtin_amdgcn_mfma_f32_16x16x32_bf16(ah[mt], bl, acc[mt][ntw], 0, 0, 0);
                acc[mt][ntw] = __builtin_amdgcn_mfma_f32_16x16x32_bf16(al[mt], bh, acc[mt][ntw], 0, 0, 0);
            }
        }
    }

#pragma unroll
    for (int ntw = 0; ntw < NTW; ++ntw) {
        int ntg = wave * NTW + ntw;
        int col = ntg * 16 + nl;
        float ctv[P];
#pragma unroll
        for (int pp = 0; pp < P; ++pp)
            ctv[pp] = cterm[(size_t)(bb * N_ + p0 + pp) * COUT + col];
        float pmax[P];
#pragma unroll
        for (int pp = 0; pp < P; ++pp) pmax[pp] = -INFINITY;
#pragma unroll
        for (int mt = 0; mt < MT; ++mt) {
            f32x4 a4 = acc[mt][ntw];
            float m3 = fmaxf(fmaxf(a4.x, a4.y), fmaxf(a4.z, a4.w));
            int p = (mt * 4 + quad) / 5;
#pragma unroll
            for (int pp = 0; pp < P; ++pp)
                pmax[pp] = (p == pp) ? fmaxf(pmax[pp], m3) : pmax[pp];
        }
#pragma unroll
        for (int pp = 0; pp < P; ++pp) {
            float m = pmax[pp];
            m = fmaxf(m, __shfl_xor(m, 16));
            m = fmaxf(m, __shfl_xor(m, 32));
            float val = m + ctv[pp];
            val = (val >= 0.f) ? val : 0.2f * val;
            if (lane < 16) out[(size_t)(bb * N_ + p0 + pp) * COUT + col] = val;
        }
    }
}

// ---------------------------------------------------------------- fp32 edge conv (L1 only)
template <int CIN, int COUT, int OO>
__global__ __launch_bounds__(COUT / OO) void conv_kernel(
    const float* __restrict__ x, const int* __restrict__ idx,
    const float* __restrict__ wdT, const float* __restrict__ wcdT,
    const float* __restrict__ bias2, float* __restrict__ out) {
    constexpr int TH = COUT / OO;
    __shared__ __align__(16) float nb[K_][CIN];
    __shared__ float ctr[CIN];
    __shared__ int nidx[K_];
    int p = blockIdx.x;
    int bb = p >> 10;
    int t = threadIdx.x;
    if (t < K_) nidx[t] = idx[(size_t)p * K_ + t];
    for (int c = t; c < CIN; c += TH) ctr[c] = x[(size_t)p * CIN + c];
    __syncthreads();
    for (int e = t; e < K_ * CIN; e += TH) {
        int k = e / CIN, c = e % CIN;
        nb[k][c] = x[(size_t)(bb * N_ + nidx[k]) * CIN + c];
    }
    __syncthreads();

    float tacc[OO];
    float acc[OO][K_];
#pragma unroll
    for (int oo = 0; oo < OO; ++oo) {
        tacc[oo] = bias2[t + oo * TH];
#pragma unroll
        for (int k = 0; k < K_; ++k) acc[oo][k] = 0.f;
    }
    for (int i = 0; i < CIN; ++i) {
        float cv = ctr[i];
#pragma unroll
        for (int oo = 0; oo < OO; ++oo) tacc[oo] += wcdT[i * COUT + t + oo * TH] * cv;
    }
    for (int i = 0; i < CIN; ++i) {
        float w[OO];
#pragma unroll
        for (int oo = 0; oo < OO; ++oo) w[oo] = wdT[i * COUT + t + oo * TH];
#pragma unroll
        for (int k = 0; k < K_; ++k) {
            float nv = nb[k][i];
#pragma unroll
            for (int oo = 0; oo < OO; ++oo) acc[oo][k] += w[oo] * nv;
        }
    }
#pragma unroll
    for (int oo = 0; oo < OO; ++oo) {
        float mx = -INFINITY;
#pragma unroll
        for (int k = 0; k < K_; ++k) {
            float val = acc[oo][k] + tacc[oo];
            val = (val >= 0.f) ? val : 0.2f * val;
            mx = fmaxf(mx, val);
        }
        out[(size_t)p * COUT + t + oo * TH] = mx;
    }
}

// ---------------------------------------------------------------- global max pool
template <int C>
__global__ __launch_bounds__(256) void pool_kernel(const float* __restrict__ h,
                                                   float* __restrict__ f, int off) {
    __shared__ float red[4][64];
    int bb = blockIdx.x / (C / 64);
    int c0 = (blockIdx.x % (C / 64)) * 64;
    int lane = threadIdx.x & 63, sl = threadIdx.x >> 6;
    int c = c0 + lane;
    const float* hb = h + (size_t)bb * N_ * C;
    float mx = -INFINITY;
    for (int n = sl * 256; n < sl * 256 + 256; ++n) mx = fmaxf(mx, hb[(size_t)n * C + c]);
    red[sl][lane] = mx;
    __syncthreads();
    if (sl == 0) {
        mx = fmaxf(fmaxf(red[0][lane], red[1][lane]), fmaxf(red[2][lane], red[3][lane]));
        f[bb * 384 + off + c] = mx;
    }
}

// ---------------------------------------------------------------- FC tail
__global__ __launch_bounds__(128) void fc_tail(
    const float* __restrict__ f, const float* __restrict__ f1w,
    const float* __restrict__ f1b, const float* __restrict__ n1g,
    const float* __restrict__ n1b, const float* __restrict__ n1m,
    const float* __restrict__ n1v, const float* __restrict__ f2w,
    const float* __restrict__ f2b, const float* __restrict__ n2g,
    const float* __restrict__ n2b, const float* __restrict__ n2m,
    const float* __restrict__ n2v, const float* __restrict__ f3w,
    const float* __restrict__ f3b, float* __restrict__ out) {
    __shared__ float fb[384];
    __shared__ float s1[128];
    __shared__ float s2[16];
    int bb = blockIdx.x, t = threadIdx.x;
    for (int j = t; j < 384; j += 128) fb[j] = f[bb * 384 + j];
    __syncthreads();
    float a = f1b[t];
    for (int j = 0; j < 384; ++j) a += f1w[t * 384 + j] * fb[j];
    a = (a - n1m[t]) * (n1g[t] / sqrtf(n1v[t] + EPS_)) + n1b[t];
    s1[t] = fmaxf(a, 0.f);
    __syncthreads();
    if (t < 16) {
        float a2 = f2b[t];
        for (int j = 0; j < 128; ++j) a2 += f2w[t * 128 + j] * s1[j];
        a2 = (a2 - n2m[t]) * (n2g[t] / sqrtf(n2v[t] + EPS_)) + n2b[t];
        s2[t] = fmaxf(a2, 0.f);
    }
    __syncthreads();
    if (t == 0) {
        float a3 = f3b[0];
        for (int j = 0; j < 16; ++j) a3 += f3w[j] * s2[j];
        out[bb] = a3;
    }
}

// ---------------------------------------------------------------- launch
extern "C" void kernel_launch(void* const* d_in, const int* in_sizes, int n_in,
                              void* d_out, int out_size, void* d_ws, size_t ws_size,
                              hipStream_t stream) {
    const float* x = (const float*)d_in[0];
    const float* cw[4] = {(const float*)d_in[1], (const float*)d_in[6],
                          (const float*)d_in[11], (const float*)d_in[16]};
    const float* cg[4] = {(const float*)d_in[2], (const float*)d_in[7],
                          (const float*)d_in[12], (const float*)d_in[17]};
    const float* cb[4] = {(const float*)d_in[3], (const float*)d_in[8],
                          (const float*)d_in[13], (const float*)d_in[18]};
    const float* cm[4] = {(const float*)d_in[4], (const float*)d_in[9],
                          (const float*)d_in[14], (const float*)d_in[19]};
    const float* cv[4] = {(const float*)d_in[5], (const float*)d_in[10],
                          (const float*)d_in[15], (const float*)d_in[20]};
    const float* f1w = (const float*)d_in[21];
    const float* f1b = (const float*)d_in[22];
    const float* n1g = (const float*)d_in[23];
    const float* n1b = (const float*)d_in[24];
    const float* n1m = (const float*)d_in[25];
    const float* n1v = (const float*)d_in[26];
    const float* f2w = (const float*)d_in[27];
    const float* f2b = (const float*)d_in[28];
    const float* n2g = (const float*)d_in[29];
    const float* n2b = (const float*)d_in[30];
    const float* n2m = (const float*)d_in[31];
    const float* n2v = (const float*)d_in[32];
    const float* f3w = (const float*)d_in[33];
    const float* f3b = (const float*)d_in[34];
    float* out = (float*)d_out;

    char* ws = (char*)d_ws;
    size_t off = 0;
    auto alloc = [&](size_t bytes) {
        void* p = ws + off;
        off += (bytes + 255) & ~(size_t)255;
        return p;
    };
    float* sq = (float*)alloc(B_ * N_ * 4);
    int* idx = (int*)alloc((size_t)B_ * N_ * K_ * 4);
    float* h1 = (float*)alloc((size_t)B_ * N_ * 64 * 4);
    float* h2 = (float*)alloc((size_t)B_ * N_ * 64 * 4);
    float* h3 = (float*)alloc((size_t)B_ * N_ * 128 * 4);
    float* h4 = (float*)alloc((size_t)B_ * N_ * 256 * 4);
    float* wd = (float*)alloc(128 * 256 * 4);
    float* wcd = (float*)alloc(128 * 256 * 4);
    float* b2 = (float*)alloc(256 * 4);
    float* f = (float*)alloc(B_ * 384 * 4);
    unsigned short* Wh = (unsigned short*)alloc(128 * 256 * 2);
    unsigned short* Wl = (unsigned short*)alloc(128 * 256 * 2);
    float* cterm = (float*)alloc((size_t)B_ * N_ * 256 * 4);
    unsigned short* Hh = (unsigned short*)alloc((size_t)B_ * N_ * 128 * 2);
    unsigned short* Hl = (unsigned short*)alloc((size_t)B_ * N_ * 128 * 2);
    (void)ws_size; (void)in_sizes; (void)n_in; (void)out_size;

    const int KB = B_ * (N_ / 8);   // knn grid (8 rows per block)
    const int SG = (B_ * N_) / 256; // split grid

    // ---- layer 1: 3 -> 64 (knn via MFMA on padded CP=32; conv fp32)
    split_kernel<3, 32><<<SG, 256, 0, stream>>>(x, Hh, Hl, sq);
    knn_kernel<32><<<KB, 256, 0, stream>>>(Hh, Hl, sq, idx);
    prep_kernel<3, 64><<<1, 256, 0, stream>>>(cw[0], cg[0], cb[0], cm[0], cv[0], wd, wcd, b2);
    conv_kernel<3, 64, 1><<<B_ * N_, 64, 0, stream>>>(x, idx, wd, wcd, b2, h1);

    // ---- layer 2: 64 -> 64 (MFMA)
    split_kernel<64, 64><<<SG, 256, 0, stream>>>(h1, Hh, Hl, sq);
    knn_kernel<64><<<KB, 256, 0, stream>>>(Hh, Hl, sq, idx);
    prep_mfma<64, 64><<<16, 256, 0, stream>>>(cw[1], cg[1], cb[1], cm[1], cv[1], Wh, Wl, wcd, b2);
    cterm_kernel<64, 64, 8><<<B_ * N_ / 8, 64, 0, stream>>>(h1, wcd, b2, cterm);
    convm_kernel<64, 64, 8><<<B_ * N_ / 8, 256, 0, stream>>>(Hh, Hl, idx, Wh, Wl, cterm, h2);

    // ---- layer 3: 64 -> 128 (MFMA)
    split_kernel<64, 64><<<SG, 256, 0, stream>>>(h2, Hh, Hl, sq);
    knn_kernel<64><<<KB, 256, 0, stream>>>(Hh, Hl, sq, idx);
    prep_mfma<64, 128><<<32, 256, 0, stream>>>(cw[2], cg[2], cb[2], cm[2], cv[2], Wh, Wl, wcd, b2);
    cterm_kernel<64, 128, 8><<<B_ * N_ / 8, 128, 0, stream>>>(h2, wcd, b2, cterm);
    convm_kernel<64, 128, 8><<<B_ * N_ / 8, 256, 0, stream>>>(Hh, Hl, idx, Wh, Wl, cterm, h3);

    // ---- layer 4: 128 -> 256 (MFMA)
    split_kernel<128, 128><<<SG, 256, 0, stream>>>(h3, Hh, Hl, sq);
    knn_kernel<128><<<KB, 256, 0, stream>>>(Hh, Hl, sq, idx);
    prep_mfma<128, 256><<<128, 256, 0, stream>>>(cw[3], cg[3], cb[3], cm[3], cv[3], Wh, Wl, wcd, b2);
    cterm_kernel<128, 256, 8><<<B_ * N_ / 8, 256, 0, stream>>>(h3, wcd, b2, cterm);
    convm_kernel<128, 256, 4><<<B_ * N_ / 4, 256, 0, stream>>>(Hh, Hl, idx, Wh, Wl, cterm, h4);

    // ---- pooling + FC tail
    pool_kernel<128><<<B_ * 2, 256, 0, stream>>>(h3, f, 0);
    pool_kernel<256><<<B_ * 4, 256, 0, stream>>>(h4, f, 128);
    fc_tail<<<B_, 128, 0, stream>>>(f, f1w, f1b, n1g, n1b, n1m, n1v, f2w, f2b, n2g, n2b,
                                    n2m, n2v, f3w, f3b, out);
}

// Round 6
// 595.529 us; speedup vs baseline: 1.1375x; 1.1375x over previous
//
#include <hip/hip_runtime.h>
#include <math.h>

constexpr int B_ = 8;
constexpr int N_ = 1024;
constexpr int K_ = 20;
constexpr float EPS_ = 1e-5f;

typedef __attribute__((ext_vector_type(8))) short short8;
typedef __attribute__((ext_vector_type(4))) float f32x4;
typedef unsigned long long u64;

// hi/lo bf16 split (RNE both halves)
__device__ __forceinline__ void bf16split(float x, unsigned short& h, unsigned short& l) {
    unsigned u = __float_as_uint(x);
    unsigned rh = (u + 0x7FFFu + ((u >> 16) & 1u)) >> 16;
    h = (unsigned short)rh;
    float lof = x - __uint_as_float(rh << 16);
    unsigned ul = __float_as_uint(lof);
    l = (unsigned short)((ul + 0x7FFFu + ((ul >> 16) & 1u)) >> 16);
}

// ---------------------------------------------------------------- split + sq
template <int C, int CP>
__global__ __launch_bounds__(256) void split_kernel(const float* __restrict__ h,
                                                    unsigned short* __restrict__ Hh,
                                                    unsigned short* __restrict__ Hl,
                                                    float* __restrict__ sq) {
    int p = blockIdx.x * 256 + threadIdx.x;
    if (p >= B_ * N_) return;
    const float* r = h + (size_t)p * C;
    unsigned short hb[CP], lb[CP];
    float s = 0.f;
#pragma unroll
    for (int c = 0; c < C; ++c) {
        float v = r[c];
        s += v * v;
        bf16split(v, hb[c], lb[c]);
    }
#pragma unroll
    for (int c = C; c < CP; ++c) { hb[c] = 0; lb[c] = 0; }
    sq[p] = s;
#pragma unroll
    for (int i = 0; i < CP / 8; ++i) {
        *(short8*)&Hh[(size_t)p * CP + 8 * i] = *(const short8*)&hb[8 * i];
        *(short8*)&Hl[(size_t)p * CP + 8 * i] = *(const short8*)&lb[8 * i];
    }
}

// ---------------------------------------------------------------- distance GEMM
// dist[b][r][c] = 2*x_r.x_c - sq_r - sq_c   (128x128 tile per block, LDS-staged,
// split-bf16 Markidis 3-MFMA).  Grid: 8 batches x 8 m-bands x 8 n-bands = 512.
template <int CP>
__global__ __launch_bounds__(256) void distg_kernel(const unsigned short* __restrict__ Hh,
                                                    const unsigned short* __restrict__ Hl,
                                                    const float* __restrict__ sq,
                                                    float* __restrict__ dist) {
    constexpr int KC = CP / 32;
    constexpr int STR = 40;  // shorts/row: 16B reads land conflict-free
    __shared__ unsigned short As[2][128 * STR];
    __shared__ unsigned short Bs[2][128 * STR];
    int t = threadIdx.x;
    int bid = blockIdx.x;
    int bb = bid >> 6;
    int r0 = ((bid >> 3) & 7) * 128;
    int c0 = (bid & 7) * 128;
    size_t base = (size_t)bb * N_;
    int lane = t & 63, wave = t >> 6, quad = lane >> 4, nl = lane & 15;
    int wm = wave >> 1, wn = wave & 1;

    f32x4 acc[4][4];
#pragma unroll
    for (int mt = 0; mt < 4; ++mt)
#pragma unroll
        for (int nt = 0; nt < 4; ++nt) acc[mt][nt] = (f32x4){0.f, 0.f, 0.f, 0.f};

    for (int kc = 0; kc < KC; ++kc) {
        if (kc) __syncthreads();
#pragma unroll
        for (int i = 0; i < 2; ++i) {
            int cid = t + i * 256;             // 512 chunks of 8 shorts
            int row = cid >> 2, j = cid & 3;
            size_t asrc = (base + r0 + row) * CP + kc * 32 + 8 * j;
            size_t bsrc = (base + c0 + row) * CP + kc * 32 + 8 * j;
            int dst = row * STR + 8 * j;
            *(short8*)&As[0][dst] = *(const short8*)&Hh[asrc];
            *(short8*)&As[1][dst] = *(const short8*)&Hl[asrc];
            *(short8*)&Bs[0][dst] = *(const short8*)&Hh[bsrc];
            *(short8*)&Bs[1][dst] = *(const short8*)&Hl[bsrc];
        }
        __syncthreads();
        short8 ah[4], al[4];
#pragma unroll
        for (int mt = 0; mt < 4; ++mt) {
            int off = (wm * 64 + mt * 16 + nl) * STR + quad * 8;
            ah[mt] = *(const short8*)&As[0][off];
            al[mt] = *(const short8*)&As[1][off];
        }
#pragma unroll
        for (int nt = 0; nt < 4; ++nt) {
            int off = (wn * 64 + nt * 16 + nl) * STR + quad * 8;
            short8 bh = *(const short8*)&Bs[0][off];
            short8 bl = *(const short8*)&Bs[1][off];
#pragma unroll
            for (int mt = 0; mt < 4; ++mt) {
                acc[mt][nt] = __builtin_amdgcn_mfma_f32_16x16x32_bf16(ah[mt], bh, acc[mt][nt], 0, 0, 0);
                acc[mt][nt] = __builtin_amdgcn_mfma_f32_16x16x32_bf16(ah[mt], bl, acc[mt][nt], 0, 0, 0);
                acc[mt][nt] = __builtin_amdgcn_mfma_f32_16x16x32_bf16(al[mt], bh, acc[mt][nt], 0, 0, 0);
            }
        }
    }
    float sqc[4];
#pragma unroll
    for (int nt = 0; nt < 4; ++nt) sqc[nt] = sq[base + c0 + wn * 64 + nt * 16 + nl];
    float* dbase = dist + (size_t)bb * N_ * N_;
#pragma unroll
    for (int mt = 0; mt < 4; ++mt) {
#pragma unroll
        for (int r = 0; r < 4; ++r) {
            int row = r0 + wm * 64 + mt * 16 + quad * 4 + r;
            float sqr = sq[base + row];
#pragma unroll
            for (int nt = 0; nt < 4; ++nt)
                dbase[(size_t)row * N_ + c0 + wn * 64 + nt * 16 + nl] =
                    2.f * acc[mt][nt][r] - sqr - sqc[nt];
        }
    }
}

// ---------------------------------------------------------------- top-20 select
__device__ __forceinline__ unsigned int fkey(float f) {
    unsigned int u = __float_as_uint(f);
    return (u & 0x80000000u) ? ~u : (u | 0x80000000u);
}

__device__ __forceinline__ u64 tree16(const u64* v) {
    u64 t0[8];
#pragma unroll
    for (int s = 0; s < 8; ++s) t0[s] = v[2 * s] > v[2 * s + 1] ? v[2 * s] : v[2 * s + 1];
#pragma unroll
    for (int s = 0; s < 4; ++s) t0[s] = t0[2 * s] > t0[2 * s + 1] ? t0[2 * s] : t0[2 * s + 1];
    t0[0] = t0[0] > t0[1] ? t0[0] : t0[1];
    t0[2] = t0[2] > t0[3] ? t0[2] : t0[3];
    return t0[0] > t0[2] ? t0[0] : t0[2];
}

__global__ __launch_bounds__(256) void sel_kernel(const float* __restrict__ dist,
                                                  int* __restrict__ idx) {
    int t = threadIdx.x;
    int bb = blockIdx.x / (N_ / 8);
    int r0 = (blockIdx.x % (N_ / 8)) * 8;
    int wave = t >> 6, lane = t & 63;
    int row0 = r0 + 2 * wave, row1 = row0 + 1;
    const float* d0 = dist + ((size_t)bb * N_ + row0) * N_;
    const float* d1 = dist + ((size_t)bb * N_ + row1) * N_;
    int c0 = lane * 16;
    u64 v0[16], v1[16];
#pragma unroll
    for (int i = 0; i < 4; ++i) {
        float4 a = *(const float4*)&d0[c0 + 4 * i];
        float4 b = *(const float4*)&d1[c0 + 4 * i];
        float av[4] = {a.x, a.y, a.z, a.w};
        float bv[4] = {b.x, b.y, b.z, b.w};
#pragma unroll
        for (int e = 0; e < 4; ++e) {
            int c = c0 + 4 * i + e;
            v0[4 * i + e] = ((u64)fkey(av[e]) << 32) | (unsigned int)(~c);
            v1[4 * i + e] = ((u64)fkey(bv[e]) << 32) | (unsigned int)(~c);
        }
    }
    int* op0 = idx + ((size_t)bb * N_ + row0) * K_;
    int* op1 = idx + ((size_t)bb * N_ + row1) * K_;
    for (int it = 0; it < K_; ++it) {
        u64 m0 = tree16(v0), m1 = tree16(v1);
#pragma unroll
        for (int off = 32; off; off >>= 1) {
            u64 o0 = __shfl_xor(m0, off);
            u64 o1 = __shfl_xor(m1, off);
            m0 = o0 > m0 ? o0 : m0;
            m1 = o1 > m1 ? o1 : m1;
        }
        if (lane == 0) {
            op0[it] = (int)(~(unsigned int)m0);
            op1[it] = (int)(~(unsigned int)m1);
        }
#pragma unroll
        for (int j = 0; j < 16; ++j) {
            v0[j] = (v0[j] == m0) ? 0ull : v0[j];
            v1[j] = (v1[j] == m1) ? 0ull : v1[j];
        }
    }
}

// ---------------------------------------------------------------- fp32 weight prep (L1)
template <int CIN, int COUT>
__global__ __launch_bounds__(256) void prep_kernel(const float* __restrict__ w,
                                                   const float* __restrict__ g,
                                                   const float* __restrict__ bb,
                                                   const float* __restrict__ m,
                                                   const float* __restrict__ v,
                                                   float* __restrict__ wdT,
                                                   float* __restrict__ wcdT,
                                                   float* __restrict__ bias2) {
    int e = blockIdx.x * 256 + threadIdx.x;
    if (e >= CIN * COUT) return;
    int o = e % COUT;
    int i = e / COUT;
    float a = g[o] / sqrtf(v[o] + EPS_);
    float wd = w[o * 2 * CIN + i];
    wdT[e] = a * wd;
    wcdT[e] = a * (w[o * 2 * CIN + CIN + i] - wd);
    if (i == 0) bias2[o] = bb[o] - m[o] * a;
}

// ---------------------------------------------------------------- MFMA weight prep
template <int CIN, int COUT>
__global__ __launch_bounds__(256) void prep_mfma(const float* __restrict__ w,
                                                 const float* __restrict__ g,
                                                 const float* __restrict__ bb,
                                                 const float* __restrict__ m,
                                                 const float* __restrict__ v,
                                                 unsigned short* __restrict__ Wh,
                                                 unsigned short* __restrict__ Wl,
                                                 float* __restrict__ wcdT,
                                                 float* __restrict__ bias2) {
    int e = blockIdx.x * 256 + threadIdx.x;
    if (e >= CIN * COUT) return;
    int n = e % COUT, k = e / COUT;
    float a = g[n] / sqrtf(v[n] + EPS_);
    float wdv = a * w[n * 2 * CIN + k];
    unsigned short h, l;
    bf16split(wdv, h, l);
    int kc = k >> 5, ko = k & 31, quad = ko >> 3, j = ko & 7;
    int nt = n >> 4, nl = n & 15;
    constexpr int NT = COUT / 16;
    size_t pos = ((size_t)(kc * NT + nt) * 64 + quad * 16 + nl) * 8 + j;
    Wh[pos] = h;
    Wl[pos] = l;
    wcdT[k * COUT + n] = a * (w[n * 2 * CIN + CIN + k] - w[n * 2 * CIN + k]);
    if (k == 0) bias2[n] = bb[n] - m[n] * a;
}

// ---------------------------------------------------------------- ctr-term (fp32)
template <int CIN, int COUT, int PP>
__global__ __launch_bounds__(COUT) void cterm_kernel(const float* __restrict__ x,
                                                     const float* __restrict__ wcdT,
                                                     const float* __restrict__ bias2,
                                                     float* __restrict__ ct) {
    __shared__ float ctr[PP][CIN];
    int p0 = blockIdx.x * PP;
    int t = threadIdx.x;
    for (int e = t; e < PP * CIN; e += COUT)
        ctr[e / CIN][e % CIN] = x[(size_t)p0 * CIN + e];
    __syncthreads();
    float acc[PP];
#pragma unroll
    for (int pp = 0; pp < PP; ++pp) acc[pp] = bias2[t];
    for (int i = 0; i < CIN; ++i) {
        float w = wcdT[i * COUT + t];
#pragma unroll
        for (int pp = 0; pp < PP; ++pp) acc[pp] = fmaf(w, ctr[pp][i], acc[pp]);
    }
#pragma unroll
    for (int pp = 0; pp < PP; ++pp) ct[(size_t)(p0 + pp) * COUT + t] = acc[pp];
}

// ---------------------------------------------------------------- MFMA edge conv
template <int CIN, int COUT, int P>
__global__ __launch_bounds__(256) void convm_kernel(const unsigned short* __restrict__ Hh,
                                                    const unsigned short* __restrict__ Hl,
                                                    const int* __restrict__ idx,
                                                    const unsigned short* __restrict__ Wh,
                                                    const unsigned short* __restrict__ Wl,
                                                    const float* __restrict__ cterm,
                                                    float* __restrict__ out) {
    constexpr int ROWS = P * K_;
    constexpr int MT = ROWS / 16;
    constexpr int NT = COUT / 16;
    constexpr int NTW = NT / 4;
    constexpr int KC = CIN / 32;
    constexpr int STR = CIN + 8;
    __shared__ unsigned short Ahi[ROWS * STR];
    __shared__ unsigned short Alo[ROWS * STR];
    __shared__ int nidx[ROWS];

    int t = threadIdx.x;
    int bb = blockIdx.x / (N_ / P);
    int p0 = (blockIdx.x % (N_ / P)) * P;

    if (t < ROWS) nidx[t] = idx[((size_t)(bb * N_ + p0 + t / K_)) * K_ + t % K_];
    __syncthreads();

    constexpr int CH8 = ROWS * (CIN / 8);
    for (int c = t; c < CH8; c += 256) {
        int r = c / (CIN / 8), cc = c % (CIN / 8);
        size_t src = ((size_t)(bb * N_ + nidx[r])) * CIN + 8 * cc;
        *(short8*)&Ahi[r * STR + 8 * cc] = *(const short8*)&Hh[src];
        *(short8*)&Alo[r * STR + 8 * cc] = *(const short8*)&Hl[src];
    }
    __syncthreads();

    int lane = t & 63, wave = t >> 6, quad = lane >> 4, nl = lane & 15;

    f32x4 acc[MT][NTW];
#pragma unroll
    for (int mt = 0; mt < MT; ++mt)
#pragma unroll
        for (int n = 0; n < NTW; ++n) acc[mt][n] = (f32x4){0.f, 0.f, 0.f, 0.f};

#pragma unroll
    for (int kc = 0; kc < KC; ++kc) {
        short8 ah[MT], al[MT];
#pragma unroll
        for (int mt = 0; mt < MT; ++mt) {
            int off = (mt * 16 + nl) * STR + kc * 32 + quad * 8;
            ah[mt] = *(const short8*)&Ahi[off];
            al[mt] = *(const short8*)&Alo[off];
        }
#pragma unroll
        for (int ntw = 0; ntw < NTW; ++ntw) {
            int ntg = wave * NTW + ntw;
            const short8 bh = *(const short8*)&Wh[((size_t)(kc * NT + ntg) * 64 + lane) * 8];
            const short8 bl = *(const short8*)&Wl[((size_t)(kc * NT + ntg) * 64 + lane) * 8];
#pragma unroll
            for (int mt = 0; mt < MT; ++mt) {
                acc[mt][ntw] = __builtin_amdgcn_mfma_f32_16x16x32_bf16(ah[mt], bh, acc[mt][ntw], 0, 0, 0);
                acc[mt][ntw] = __builtin_amdgcn_mfma_f32_16x16x32_bf16(ah[mt], bl, acc[mt][ntw], 0, 0, 0);
                acc[mt][ntw] = __builtin_amdgcn_mfma_f32_16x16x32_bf16(al[mt], bh, acc[mt][ntw], 0, 0, 0);
            }
        }
    }

#pragma unroll
    for (int ntw = 0; ntw < NTW; ++ntw) {
        int ntg = wave * NTW + ntw;
        int col = ntg * 16 + nl;
        float ctv[P];
#pragma unroll
        for (int pp = 0; pp < P; ++pp)
            ctv[pp] = cterm[(size_t)(bb * N_ + p0 + pp) * COUT + col];
        float pmax[P];
#pragma unroll
        for (int pp = 0; pp < P; ++pp) pmax[pp] = -INFINITY;
#pragma unroll
        for (int mt = 0; mt < MT; ++mt) {
            f32x4 a4 = acc[mt][ntw];
            float m3 = fmaxf(fmaxf(a4.x, a4.y), fmaxf(a4.z, a4.w));
            int p = (mt * 4 + quad) / 5;
#pragma unroll
            for (int pp = 0; pp < P; ++pp)
                pmax[pp] = (p == pp) ? fmaxf(pmax[pp], m3) : pmax[pp];
        }
#pragma unroll
        for (int pp = 0; pp < P; ++pp) {
            float m = pmax[pp];
            m = fmaxf(m, __shfl_xor(m, 16));
            m = fmaxf(m, __shfl_xor(m, 32));
            float val = m + ctv[pp];
            val = (val >= 0.f) ? val : 0.2f * val;
            if (lane < 16) out[(size_t)(bb * N_ + p0 + pp) * COUT + col] = val;
        }
    }
}

// ---------------------------------------------------------------- fp32 edge conv (L1 only)
template <int CIN, int COUT, int OO>
__global__ __launch_bounds__(COUT / OO) void conv_kernel(
    const float* __restrict__ x, const int* __restrict__ idx,
    const float* __restrict__ wdT, const float* __restrict__ wcdT,
    const float* __restrict__ bias2, float* __restrict__ out) {
    constexpr int TH = COUT / OO;
    __shared__ __align__(16) float nb[K_][CIN];
    __shared__ float ctr[CIN];
    __shared__ int nidx[K_];
    int p = blockIdx.x;
    int bb = p >> 10;
    int t = threadIdx.x;
    if (t < K_) nidx[t] = idx[(size_t)p * K_ + t];
    for (int c = t; c < CIN; c += TH) ctr[c] = x[(size_t)p * CIN + c];
    __syncthreads();
    for (int e = t; e < K_ * CIN; e += TH) {
        int k = e / CIN, c = e % CIN;
        nb[k][c] = x[(size_t)(bb * N_ + nidx[k]) * CIN + c];
    }
    __syncthreads();

    float tacc[OO];
    float acc[OO][K_];
#pragma unroll
    for (int oo = 0; oo < OO; ++oo) {
        tacc[oo] = bias2[t + oo * TH];
#pragma unroll
        for (int k = 0; k < K_; ++k) acc[oo][k] = 0.f;
    }
    for (int i = 0; i < CIN; ++i) {
        float cv = ctr[i];
#pragma unroll
        for (int oo = 0; oo < OO; ++oo) tacc[oo] += wcdT[i * COUT + t + oo * TH] * cv;
    }
    for (int i = 0; i < CIN; ++i) {
        float w[OO];
#pragma unroll
        for (int oo = 0; oo < OO; ++oo) w[oo] = wdT[i * COUT + t + oo * TH];
#pragma unroll
        for (int k = 0; k < K_; ++k) {
            float nv = nb[k][i];
#pragma unroll
            for (int oo = 0; oo < OO; ++oo) acc[oo][k] += w[oo] * nv;
        }
    }
#pragma unroll
    for (int oo = 0; oo < OO; ++oo) {
        float mx = -INFINITY;
#pragma unroll
        for (int k = 0; k < K_; ++k) {
            float val = acc[oo][k] + tacc[oo];
            val = (val >= 0.f) ? val : 0.2f * val;
            mx = fmaxf(mx, val);
        }
        out[(size_t)p * COUT + t + oo * TH] = mx;
    }
}

// ---------------------------------------------------------------- global max pool
template <int C>
__global__ __launch_bounds__(256) void pool_kernel(const float* __restrict__ h,
                                                   float* __restrict__ f, int off) {
    __shared__ float red[4][64];
    int bb = blockIdx.x / (C / 64);
    int c0 = (blockIdx.x % (C / 64)) * 64;
    int lane = threadIdx.x & 63, sl = threadIdx.x >> 6;
    int c = c0 + lane;
    const float* hb = h + (size_t)bb * N_ * C;
    float mx = -INFINITY;
    for (int n = sl * 256; n < sl * 256 + 256; ++n) mx = fmaxf(mx, hb[(size_t)n * C + c]);
    red[sl][lane] = mx;
    __syncthreads();
    if (sl == 0) {
        mx = fmaxf(fmaxf(red[0][lane], red[1][lane]), fmaxf(red[2][lane], red[3][lane]));
        f[bb * 384 + off + c] = mx;
    }
}

// ---------------------------------------------------------------- FC tail
__global__ __launch_bounds__(128) void fc_tail(
    const float* __restrict__ f, const float* __restrict__ f1w,
    const float* __restrict__ f1b, const float* __restrict__ n1g,
    const float* __restrict__ n1b, const float* __restrict__ n1m,
    const float* __restrict__ n1v, const float* __restrict__ f2w,
    const float* __restrict__ f2b, const float* __restrict__ n2g,
    const float* __restrict__ n2b, const float* __restrict__ n2m,
    const float* __restrict__ n2v, const float* __restrict__ f3w,
    const float* __restrict__ f3b, float* __restrict__ out) {
    __shared__ float fb[384];
    __shared__ float s1[128];
    __shared__ float s2[16];
    int bb = blockIdx.x, t = threadIdx.x;
    for (int j = t; j < 384; j += 128) fb[j] = f[bb * 384 + j];
    __syncthreads();
    float a = f1b[t];
    for (int j = 0; j < 384; ++j) a += f1w[t * 384 + j] * fb[j];
    a = (a - n1m[t]) * (n1g[t] / sqrtf(n1v[t] + EPS_)) + n1b[t];
    s1[t] = fmaxf(a, 0.f);
    __syncthreads();
    if (t < 16) {
        float a2 = f2b[t];
        for (int j = 0; j < 128; ++j) a2 += f2w[t * 128 + j] * s1[j];
        a2 = (a2 - n2m[t]) * (n2g[t] / sqrtf(n2v[t] + EPS_)) + n2b[t];
        s2[t] = fmaxf(a2, 0.f);
    }
    __syncthreads();
    if (t == 0) {
        float a3 = f3b[0];
        for (int j = 0; j < 16; ++j) a3 += f3w[j] * s2[j];
        out[bb] = a3;
    }
}

// ---------------------------------------------------------------- launch
extern "C" void kernel_launch(void* const* d_in, const int* in_sizes, int n_in,
                              void* d_out, int out_size, void* d_ws, size_t ws_size,
                              hipStream_t stream) {
    const float* x = (const float*)d_in[0];
    const float* cw[4] = {(const float*)d_in[1], (const float*)d_in[6],
                          (const float*)d_in[11], (const float*)d_in[16]};
    const float* cg[4] = {(const float*)d_in[2], (const float*)d_in[7],
                          (const float*)d_in[12], (const float*)d_in[17]};
    const float* cb[4] = {(const float*)d_in[3], (const float*)d_in[8],
                          (const float*)d_in[13], (const float*)d_in[18]};
    const float* cm[4] = {(const float*)d_in[4], (const float*)d_in[9],
                          (const float*)d_in[14], (const float*)d_in[19]};
    const float* cv[4] = {(const float*)d_in[5], (const float*)d_in[10],
                          (const float*)d_in[15], (const float*)d_in[20]};
    const float* f1w = (const float*)d_in[21];
    const float* f1b = (const float*)d_in[22];
    const float* n1g = (const float*)d_in[23];
    const float* n1b = (const float*)d_in[24];
    const float* n1m = (const float*)d_in[25];
    const float* n1v = (const float*)d_in[26];
    const float* f2w = (const float*)d_in[27];
    const float* f2b = (const float*)d_in[28];
    const float* n2g = (const float*)d_in[29];
    const float* n2b = (const float*)d_in[30];
    const float* n2m = (const float*)d_in[31];
    const float* n2v = (const float*)d_in[32];
    const float* f3w = (const float*)d_in[33];
    const float* f3b = (const float*)d_in[34];
    float* out = (float*)d_out;

    char* ws = (char*)d_ws;
    size_t off = 0;
    auto alloc = [&](size_t bytes) {
        void* p = ws + off;
        off += (bytes + 255) & ~(size_t)255;
        return p;
    };
    float* sq = (float*)alloc(B_ * N_ * 4);
    int* idx = (int*)alloc((size_t)B_ * N_ * K_ * 4);
    float* h1 = (float*)alloc((size_t)B_ * N_ * 64 * 4);
    float* h2 = (float*)alloc((size_t)B_ * N_ * 64 * 4);
    float* h3 = (float*)alloc((size_t)B_ * N_ * 128 * 4);
    float* h4 = (float*)alloc((size_t)B_ * N_ * 256 * 4);
    float* wd = (float*)alloc(128 * 256 * 4);
    float* wcd = (float*)alloc(128 * 256 * 4);
    float* b2 = (float*)alloc(256 * 4);
    float* f = (float*)alloc(B_ * 384 * 4);
    unsigned short* Wh = (unsigned short*)alloc(128 * 256 * 2);
    unsigned short* Wl = (unsigned short*)alloc(128 * 256 * 2);
    unsigned short* Hh = (unsigned short*)alloc((size_t)B_ * N_ * 128 * 2);
    unsigned short* Hl = (unsigned short*)alloc((size_t)B_ * N_ * 128 * 2);
    // dist (32 MB) and cterm (8 MB) have disjoint lifetimes within a layer:
    // dist live [distg, sel]; cterm live [cterm_kernel, convm].  Overlay.
    float* dist = (float*)alloc((size_t)B_ * N_ * N_ * 4);
    float* cterm = dist;
    (void)ws_size; (void)in_sizes; (void)n_in; (void)out_size;

    const int SELG = B_ * (N_ / 8);  // select grid (8 rows/block)
    const int SG = (B_ * N_) / 256;  // split grid
    const int DG = B_ * 64;          // dist-GEMM grid (8x8 tiles/batch)

    // ---- layer 1: 3 -> 64 (knn via MFMA on padded CP=32; conv fp32)
    split_kernel<3, 32><<<SG, 256, 0, stream>>>(x, Hh, Hl, sq);
    distg_kernel<32><<<DG, 256, 0, stream>>>(Hh, Hl, sq, dist);
    sel_kernel<<<SELG, 256, 0, stream>>>(dist, idx);
    prep_kernel<3, 64><<<1, 256, 0, stream>>>(cw[0], cg[0], cb[0], cm[0], cv[0], wd, wcd, b2);
    conv_kernel<3, 64, 1><<<B_ * N_, 64, 0, stream>>>(x, idx, wd, wcd, b2, h1);

    // ---- layer 2: 64 -> 64 (MFMA)
    split_kernel<64, 64><<<SG, 256, 0, stream>>>(h1, Hh, Hl, sq);
    distg_kernel<64><<<DG, 256, 0, stream>>>(Hh, Hl, sq, dist);
    sel_kernel<<<SELG, 256, 0, stream>>>(dist, idx);
    prep_mfma<64, 64><<<16, 256, 0, stream>>>(cw[1], cg[1], cb[1], cm[1], cv[1], Wh, Wl, wcd, b2);
    cterm_kernel<64, 64, 8><<<B_ * N_ / 8, 64, 0, stream>>>(h1, wcd, b2, cterm);
    convm_kernel<64, 64, 8><<<B_ * N_ / 8, 256, 0, stream>>>(Hh, Hl, idx, Wh, Wl, cterm, h2);

    // ---- layer 3: 64 -> 128 (MFMA)
    split_kernel<64, 64><<<SG, 256, 0, stream>>>(h2, Hh, Hl, sq);
    distg_kernel<64><<<DG, 256, 0, stream>>>(Hh, Hl, sq, dist);
    sel_kernel<<<SELG, 256, 0, stream>>>(dist, idx);
    prep_mfma<64, 128><<<32, 256, 0, stream>>>(cw[2], cg[2], cb[2], cm[2], cv[2], Wh, Wl, wcd, b2);
    cterm_kernel<64, 128, 8><<<B_ * N_ / 8, 128, 0, stream>>>(h2, wcd, b2, cterm);
    convm_kernel<64, 128, 8><<<B_ * N_ / 8, 256, 0, stream>>>(Hh, Hl, idx, Wh, Wl, cterm, h3);

    // ---- layer 4: 128 -> 256 (MFMA)
    split_kernel<128, 128><<<SG, 256, 0, stream>>>(h3, Hh, Hl, sq);
    distg_kernel<128><<<DG, 256, 0, stream>>>(Hh, Hl, sq, dist);
    sel_kernel<<<SELG, 256, 0, stream>>>(dist, idx);
    prep_mfma<128, 256><<<128, 256, 0, stream>>>(cw[3], cg[3], cb[3], cm[3], cv[3], Wh, Wl, wcd, b2);
    cterm_kernel<128, 256, 8><<<B_ * N_ / 8, 256, 0, stream>>>(h3, wcd, b2, cterm);
    convm_kernel<128, 256, 4><<<B_ * N_ / 4, 256, 0, stream>>>(Hh, Hl, idx, Wh, Wl, cterm, h4);

    // ---- pooling + FC tail
    pool_kernel<128><<<B_ * 2, 256, 0, stream>>>(h3, f, 0);
    pool_kernel<256><<<B_ * 4, 256, 0, stream>>>(h4, f, 128);
    fc_tail<<<B_, 128, 0, stream>>>(f, f1w, f1b, n1g, n1b, n1m, n1v, f2w, f2b, n2g, n2b,
                                    n2m, n2v, f3w, f3b, out);
}

// Round 7
// 538.375 us; speedup vs baseline: 1.2582x; 1.1062x over previous
//
#include <hip/hip_runtime.h>
#include <math.h>

constexpr int B_ = 8;
constexpr int N_ = 1024;
constexpr int K_ = 20;
constexpr float EPS_ = 1e-5f;

typedef __attribute__((ext_vector_type(8))) short short8;
typedef __attribute__((ext_vector_type(4))) float f32x4;
typedef unsigned long long u64;

// hi/lo bf16 split (RNE both halves)
__device__ __forceinline__ void bf16split(float x, unsigned short& h, unsigned short& l) {
    unsigned u = __float_as_uint(x);
    unsigned rh = (u + 0x7FFFu + ((u >> 16) & 1u)) >> 16;
    h = (unsigned short)rh;
    float lof = x - __uint_as_float(rh << 16);
    unsigned ul = __float_as_uint(lof);
    l = (unsigned short)((ul + 0x7FFFu + ((ul >> 16) & 1u)) >> 16);
}

// ---------------------------------------------------------------- split + sq
template <int C, int CP>
__global__ __launch_bounds__(256) void split_kernel(const float* __restrict__ h,
                                                    unsigned short* __restrict__ Hh,
                                                    unsigned short* __restrict__ Hl,
                                                    float* __restrict__ sq) {
    int p = blockIdx.x * 256 + threadIdx.x;
    if (p >= B_ * N_) return;
    const float* r = h + (size_t)p * C;
    unsigned short hb[CP], lb[CP];
    float s = 0.f;
#pragma unroll
    for (int c = 0; c < C; ++c) {
        float v = r[c];
        s += v * v;
        bf16split(v, hb[c], lb[c]);
    }
#pragma unroll
    for (int c = C; c < CP; ++c) { hb[c] = 0; lb[c] = 0; }
    sq[p] = s;
#pragma unroll
    for (int i = 0; i < CP / 8; ++i) {
        *(short8*)&Hh[(size_t)p * CP + 8 * i] = *(const short8*)&hb[8 * i];
        *(short8*)&Hl[(size_t)p * CP + 8 * i] = *(const short8*)&lb[8 * i];
    }
}

// ---------------------------------------------------------------- distance GEMM
template <int CP>
__global__ __launch_bounds__(256) void distg_kernel(const unsigned short* __restrict__ Hh,
                                                    const unsigned short* __restrict__ Hl,
                                                    const float* __restrict__ sq,
                                                    float* __restrict__ dist) {
    constexpr int KC = CP / 32;
    constexpr int STR = 40;
    __shared__ unsigned short As[2][128 * STR];
    __shared__ unsigned short Bs[2][128 * STR];
    int t = threadIdx.x;
    int bid = blockIdx.x;
    int bb = bid >> 6;
    int r0 = ((bid >> 3) & 7) * 128;
    int c0 = (bid & 7) * 128;
    size_t base = (size_t)bb * N_;
    int lane = t & 63, wave = t >> 6, quad = lane >> 4, nl = lane & 15;
    int wm = wave >> 1, wn = wave & 1;

    f32x4 acc[4][4];
#pragma unroll
    for (int mt = 0; mt < 4; ++mt)
#pragma unroll
        for (int nt = 0; nt < 4; ++nt) acc[mt][nt] = (f32x4){0.f, 0.f, 0.f, 0.f};

    for (int kc = 0; kc < KC; ++kc) {
        if (kc) __syncthreads();
#pragma unroll
        for (int i = 0; i < 2; ++i) {
            int cid = t + i * 256;
            int row = cid >> 2, j = cid & 3;
            size_t asrc = (base + r0 + row) * CP + kc * 32 + 8 * j;
            size_t bsrc = (base + c0 + row) * CP + kc * 32 + 8 * j;
            int dst = row * STR + 8 * j;
            *(short8*)&As[0][dst] = *(const short8*)&Hh[asrc];
            *(short8*)&As[1][dst] = *(const short8*)&Hl[asrc];
            *(short8*)&Bs[0][dst] = *(const short8*)&Hh[bsrc];
            *(short8*)&Bs[1][dst] = *(const short8*)&Hl[bsrc];
        }
        __syncthreads();
        short8 ah[4], al[4];
#pragma unroll
        for (int mt = 0; mt < 4; ++mt) {
            int off = (wm * 64 + mt * 16 + nl) * STR + quad * 8;
            ah[mt] = *(const short8*)&As[0][off];
            al[mt] = *(const short8*)&As[1][off];
        }
#pragma unroll
        for (int nt = 0; nt < 4; ++nt) {
            int off = (wn * 64 + nt * 16 + nl) * STR + quad * 8;
            short8 bh = *(const short8*)&Bs[0][off];
            short8 bl = *(const short8*)&Bs[1][off];
#pragma unroll
            for (int mt = 0; mt < 4; ++mt) {
                acc[mt][nt] = __builtin_amdgcn_mfma_f32_16x16x32_bf16(ah[mt], bh, acc[mt][nt], 0, 0, 0);
                acc[mt][nt] = __builtin_amdgcn_mfma_f32_16x16x32_bf16(ah[mt], bl, acc[mt][nt], 0, 0, 0);
                acc[mt][nt] = __builtin_amdgcn_mfma_f32_16x16x32_bf16(al[mt], bh, acc[mt][nt], 0, 0, 0);
            }
        }
    }
    float sqc[4];
#pragma unroll
    for (int nt = 0; nt < 4; ++nt) sqc[nt] = sq[base + c0 + wn * 64 + nt * 16 + nl];
    float* dbase = dist + (size_t)bb * N_ * N_;
#pragma unroll
    for (int mt = 0; mt < 4; ++mt) {
#pragma unroll
        for (int r = 0; r < 4; ++r) {
            int row = r0 + wm * 64 + mt * 16 + quad * 4 + r;
            float sqr = sq[base + row];
#pragma unroll
            for (int nt = 0; nt < 4; ++nt)
                dbase[(size_t)row * N_ + c0 + wn * 64 + nt * 16 + nl] =
                    2.f * acc[mt][nt][r] - sqr - sqc[nt];
        }
    }
}

// ---------------------------------------------------------------- top-20 select
__device__ __forceinline__ unsigned int fkey(float f) {
    unsigned int u = __float_as_uint(f);
    return (u & 0x80000000u) ? ~u : (u | 0x80000000u);
}

__device__ __forceinline__ u64 tree16(const u64* v) {
    u64 t0[8];
#pragma unroll
    for (int s = 0; s < 8; ++s) t0[s] = v[2 * s] > v[2 * s + 1] ? v[2 * s] : v[2 * s + 1];
#pragma unroll
    for (int s = 0; s < 4; ++s) t0[s] = t0[2 * s] > t0[2 * s + 1] ? t0[2 * s] : t0[2 * s + 1];
    t0[0] = t0[0] > t0[1] ? t0[0] : t0[1];
    t0[2] = t0[2] > t0[3] ? t0[2] : t0[3];
    return t0[0] > t0[2] ? t0[0] : t0[2];
}

__global__ __launch_bounds__(256) void sel_kernel(const float* __restrict__ dist,
                                                  int* __restrict__ idx) {
    int t = threadIdx.x;
    int bb = blockIdx.x / (N_ / 8);
    int r0 = (blockIdx.x % (N_ / 8)) * 8;
    int wave = t >> 6, lane = t & 63;
    int row0 = r0 + 2 * wave, row1 = row0 + 1;
    const float* d0 = dist + ((size_t)bb * N_ + row0) * N_;
    const float* d1 = dist + ((size_t)bb * N_ + row1) * N_;
    int c0 = lane * 16;
    u64 v0[16], v1[16];
#pragma unroll
    for (int i = 0; i < 4; ++i) {
        float4 a = *(const float4*)&d0[c0 + 4 * i];
        float4 b = *(const float4*)&d1[c0 + 4 * i];
        float av[4] = {a.x, a.y, a.z, a.w};
        float bv[4] = {b.x, b.y, b.z, b.w};
#pragma unroll
        for (int e = 0; e < 4; ++e) {
            int c = c0 + 4 * i + e;
            v0[4 * i + e] = ((u64)fkey(av[e]) << 32) | (unsigned int)(~c);
            v1[4 * i + e] = ((u64)fkey(bv[e]) << 32) | (unsigned int)(~c);
        }
    }
    int* op0 = idx + ((size_t)bb * N_ + row0) * K_;
    int* op1 = idx + ((size_t)bb * N_ + row1) * K_;
    for (int it = 0; it < K_; ++it) {
        u64 m0 = tree16(v0), m1 = tree16(v1);
#pragma unroll
        for (int off = 32; off; off >>= 1) {
            u64 o0 = __shfl_xor(m0, off);
            u64 o1 = __shfl_xor(m1, off);
            m0 = o0 > m0 ? o0 : m0;
            m1 = o1 > m1 ? o1 : m1;
        }
        if (lane == 0) {
            op0[it] = (int)(~(unsigned int)m0);
            op1[it] = (int)(~(unsigned int)m1);
        }
#pragma unroll
        for (int j = 0; j < 16; ++j) {
            v0[j] = (v0[j] == m0) ? 0ull : v0[j];
            v1[j] = (v1[j] == m1) ? 0ull : v1[j];
        }
    }
}

// ---------------------------------------------------------------- fp32 weight prep (L1)
template <int CIN, int COUT>
__global__ __launch_bounds__(256) void prep_kernel(const float* __restrict__ w,
                                                   const float* __restrict__ g,
                                                   const float* __restrict__ bb,
                                                   const float* __restrict__ m,
                                                   const float* __restrict__ v,
                                                   float* __restrict__ wdT,
                                                   float* __restrict__ wcdT,
                                                   float* __restrict__ bias2) {
    int e = blockIdx.x * 256 + threadIdx.x;
    if (e >= CIN * COUT) return;
    int o = e % COUT;
    int i = e / COUT;
    float a = g[o] / sqrtf(v[o] + EPS_);
    float wd = w[o * 2 * CIN + i];
    wdT[e] = a * wd;
    wcdT[e] = a * (w[o * 2 * CIN + CIN + i] - wd);
    if (i == 0) bias2[o] = bb[o] - m[o] * a;
}

// ---------------------------------------------------------------- L1 Y|Z (fp32, CIN=3)
__global__ __launch_bounds__(256) void y1z1_kernel(const float* __restrict__ x,
                                                   const float* __restrict__ wdT,
                                                   const float* __restrict__ wcdT,
                                                   const float* __restrict__ bias2,
                                                   float* __restrict__ YZ) {
    int t = threadIdx.x;
    int p = blockIdx.x * 4 + (t >> 6);
    int o = t & 63;
    float x0 = x[3 * p], x1 = x[3 * p + 1], x2 = x[3 * p + 2];
    float y = x0 * wdT[o] + x1 * wdT[64 + o] + x2 * wdT[128 + o];
    float z = bias2[o] + x0 * wcdT[o] + x1 * wcdT[64 + o] + x2 * wcdT[128 + o];
    YZ[(size_t)p * 128 + o] = y;
    YZ[(size_t)p * 128 + 64 + o] = z;
}

// ---------------------------------------------------------------- MFMA weight prep (cat [Wd ; Wc-Wd])
// B-fragment order for NOUT=2*COUT cols; bias vec: 0 for Y half, BN bias for Z half.
template <int CIN, int COUT>
__global__ __launch_bounds__(256) void prep_mfma2(const float* __restrict__ w,
                                                  const float* __restrict__ g,
                                                  const float* __restrict__ bb,
                                                  const float* __restrict__ m,
                                                  const float* __restrict__ v,
                                                  unsigned short* __restrict__ Wh,
                                                  unsigned short* __restrict__ Wl,
                                                  float* __restrict__ bias2) {
    constexpr int NOUT = 2 * COUT;
    constexpr int NT = NOUT / 16;
    int e = blockIdx.x * 256 + threadIdx.x;
    if (e >= CIN * NOUT) return;
    int n = e % NOUT, k = e / NOUT;
    int o = (n < COUT) ? n : n - COUT;
    float a = g[o] / sqrtf(v[o] + EPS_);
    float wv = (n < COUT) ? a * w[o * 2 * CIN + k]
                          : a * (w[o * 2 * CIN + CIN + k] - w[o * 2 * CIN + k]);
    unsigned short h, l;
    bf16split(wv, h, l);
    int kc = k >> 5, ko = k & 31, quad = ko >> 3, j = ko & 7;
    int nt = n >> 4, nl = n & 15;
    size_t pos = ((size_t)(kc * NT + nt) * 64 + quad * 16 + nl) * 8 + j;
    Wh[pos] = h;
    Wl[pos] = l;
    if (k == 0) bias2[n] = (n < COUT) ? 0.f : (bb[o] - m[o] * a);
}

// ---------------------------------------------------------------- Y|Z GEMM (points x NOUT)
// 128x128 tile, A (points) LDS-staged, B (weights) from L1-cached global fragments.
template <int CP, int NOUT>
__global__ __launch_bounds__(256) void gemmYZ_kernel(const unsigned short* __restrict__ Hh,
                                                     const unsigned short* __restrict__ Hl,
                                                     const unsigned short* __restrict__ Wh,
                                                     const unsigned short* __restrict__ Wl,
                                                     const float* __restrict__ bias2,
                                                     float* __restrict__ YZ) {
    constexpr int KC = CP / 32;
    constexpr int NTt = NOUT / 16;
    constexpr int STR = 40;
    __shared__ unsigned short As[2][128 * STR];
    int t = threadIdx.x;
    int m0 = blockIdx.x * 128;
    int n0 = blockIdx.y * 128;
    int lane = t & 63, wave = t >> 6, quad = lane >> 4, nl = lane & 15;
    int wm = wave >> 1, wn = wave & 1;

    f32x4 acc[4][4];
#pragma unroll
    for (int mt = 0; mt < 4; ++mt)
#pragma unroll
        for (int nt = 0; nt < 4; ++nt) acc[mt][nt] = (f32x4){0.f, 0.f, 0.f, 0.f};

    for (int kc = 0; kc < KC; ++kc) {
        if (kc) __syncthreads();
#pragma unroll
        for (int i = 0; i < 2; ++i) {
            int cid = t + i * 256;
            int row = cid >> 2, j = cid & 3;
            size_t src = ((size_t)(m0 + row)) * CP + kc * 32 + 8 * j;
            int dst = row * STR + 8 * j;
            *(short8*)&As[0][dst] = *(const short8*)&Hh[src];
            *(short8*)&As[1][dst] = *(const short8*)&Hl[src];
        }
        __syncthreads();
        short8 ah[4], al[4];
#pragma unroll
        for (int mt = 0; mt < 4; ++mt) {
            int off = (wm * 64 + mt * 16 + nl) * STR + quad * 8;
            ah[mt] = *(const short8*)&As[0][off];
            al[mt] = *(const short8*)&As[1][off];
        }
#pragma unroll
        for (int nt = 0; nt < 4; ++nt) {
            int ntg = (n0 >> 4) + wn * 4 + nt;
            size_t bpos = ((size_t)(kc * NTt + ntg) * 64 + lane) * 8;
            short8 bh = *(const short8*)&Wh[bpos];
            short8 bl = *(const short8*)&Wl[bpos];
#pragma unroll
            for (int mt = 0; mt < 4; ++mt) {
                acc[mt][nt] = __builtin_amdgcn_mfma_f32_16x16x32_bf16(ah[mt], bh, acc[mt][nt], 0, 0, 0);
                acc[mt][nt] = __builtin_amdgcn_mfma_f32_16x16x32_bf16(ah[mt], bl, acc[mt][nt], 0, 0, 0);
                acc[mt][nt] = __builtin_amdgcn_mfma_f32_16x16x32_bf16(al[mt], bh, acc[mt][nt], 0, 0, 0);
            }
        }
    }
#pragma unroll
    for (int nt = 0; nt < 4; ++nt) {
        int col = n0 + wn * 64 + nt * 16 + nl;
        float bv = bias2[col];
#pragma unroll
        for (int mt = 0; mt < 4; ++mt) {
#pragma unroll
            for (int r = 0; r < 4; ++r) {
                int row = m0 + wm * 64 + mt * 16 + quad * 4 + r;
                YZ[(size_t)row * NOUT + col] = acc[mt][nt][r] + bv;
            }
        }
    }
}

// ---------------------------------------------------------------- gather + max + lrelu
// out[p][o] = lrelu(Z[p][o] + max_k Y[nb(p,k)][o]);  Y = YZ[:,0:COUT], Z = YZ[:,COUT:].
template <int COUT>
__global__ __launch_bounds__(256) void gathermax_kernel(const float* __restrict__ YZ,
                                                        const int* __restrict__ idx,
                                                        float* __restrict__ h) {
    constexpr int NOUT = 2 * COUT;
    constexpr int PPG = 256 / COUT;
    __shared__ int nidx[PPG][K_];
    int t = threadIdx.x;
    int p0 = blockIdx.x * PPG;
    if (t < PPG * K_) nidx[t / K_][t % K_] = idx[(size_t)(p0 + t / K_) * K_ + t % K_];
    __syncthreads();
    int pg = t / COUT;
    int o = t % COUT;
    int p = p0 + pg;
    size_t ybase = (size_t)(p >> 10) << 10;  // batch row base
    float m = -INFINITY;
#pragma unroll
    for (int k = 0; k < K_; ++k)
        m = fmaxf(m, YZ[(ybase + nidx[pg][k]) * NOUT + o]);
    float val = m + YZ[(size_t)p * NOUT + COUT + o];
    val = (val >= 0.f) ? val : 0.2f * val;
    h[(size_t)p * COUT + o] = val;
}

// ---------------------------------------------------------------- global max pool
template <int C>
__global__ __launch_bounds__(256) void pool_kernel(const float* __restrict__ h,
                                                   float* __restrict__ f, int off) {
    __shared__ float red[4][64];
    int bb = blockIdx.x / (C / 64);
    int c0 = (blockIdx.x % (C / 64)) * 64;
    int lane = threadIdx.x & 63, sl = threadIdx.x >> 6;
    int c = c0 + lane;
    const float* hb = h + (size_t)bb * N_ * C;
    float mx = -INFINITY;
    for (int n = sl * 256; n < sl * 256 + 256; ++n) mx = fmaxf(mx, hb[(size_t)n * C + c]);
    red[sl][lane] = mx;
    __syncthreads();
    if (sl == 0) {
        mx = fmaxf(fmaxf(red[0][lane], red[1][lane]), fmaxf(red[2][lane], red[3][lane]));
        f[bb * 384 + off + c] = mx;
    }
}

// ---------------------------------------------------------------- FC tail
__global__ __launch_bounds__(128) void fc_tail(
    const float* __restrict__ f, const float* __restrict__ f1w,
    const float* __restrict__ f1b, const float* __restrict__ n1g,
    const float* __restrict__ n1b, const float* __restrict__ n1m,
    const float* __restrict__ n1v, const float* __restrict__ f2w,
    const float* __restrict__ f2b, const float* __restrict__ n2g,
    const float* __restrict__ n2b, const float* __restrict__ n2m,
    const float* __restrict__ n2v, const float* __restrict__ f3w,
    const float* __restrict__ f3b, float* __restrict__ out) {
    __shared__ float fb[384];
    __shared__ float s1[128];
    __shared__ float s2[16];
    int bb = blockIdx.x, t = threadIdx.x;
    for (int j = t; j < 384; j += 128) fb[j] = f[bb * 384 + j];
    __syncthreads();
    float a = f1b[t];
    for (int j = 0; j < 384; ++j) a += f1w[t * 384 + j] * fb[j];
    a = (a - n1m[t]) * (n1g[t] / sqrtf(n1v[t] + EPS_)) + n1b[t];
    s1[t] = fmaxf(a, 0.f);
    __syncthreads();
    if (t < 16) {
        float a2 = f2b[t];
        for (int j = 0; j < 128; ++j) a2 += f2w[t * 128 + j] * s1[j];
        a2 = (a2 - n2m[t]) * (n2g[t] / sqrtf(n2v[t] + EPS_)) + n2b[t];
        s2[t] = fmaxf(a2, 0.f);
    }
    __syncthreads();
    if (t == 0) {
        float a3 = f3b[0];
        for (int j = 0; j < 16; ++j) a3 += f3w[j] * s2[j];
        out[bb] = a3;
    }
}

// ---------------------------------------------------------------- launch
extern "C" void kernel_launch(void* const* d_in, const int* in_sizes, int n_in,
                              void* d_out, int out_size, void* d_ws, size_t ws_size,
                              hipStream_t stream) {
    const float* x = (const float*)d_in[0];
    const float* cw[4] = {(const float*)d_in[1], (const float*)d_in[6],
                          (const float*)d_in[11], (const float*)d_in[16]};
    const float* cg[4] = {(const float*)d_in[2], (const float*)d_in[7],
                          (const float*)d_in[12], (const float*)d_in[17]};
    const float* cb[4] = {(const float*)d_in[3], (const float*)d_in[8],
                          (const float*)d_in[13], (const float*)d_in[18]};
    const float* cm[4] = {(const float*)d_in[4], (const float*)d_in[9],
                          (const float*)d_in[14], (const float*)d_in[19]};
    const float* cv[4] = {(const float*)d_in[5], (const float*)d_in[10],
                          (const float*)d_in[15], (const float*)d_in[20]};
    const float* f1w = (const float*)d_in[21];
    const float* f1b = (const float*)d_in[22];
    const float* n1g = (const float*)d_in[23];
    const float* n1b = (const float*)d_in[24];
    const float* n1m = (const float*)d_in[25];
    const float* n1v = (const float*)d_in[26];
    const float* f2w = (const float*)d_in[27];
    const float* f2b = (const float*)d_in[28];
    const float* n2g = (const float*)d_in[29];
    const float* n2b = (const float*)d_in[30];
    const float* n2m = (const float*)d_in[31];
    const float* n2v = (const float*)d_in[32];
    const float* f3w = (const float*)d_in[33];
    const float* f3b = (const float*)d_in[34];
    float* out = (float*)d_out;

    char* ws = (char*)d_ws;
    size_t off = 0;
    auto alloc = [&](size_t bytes) {
        void* p = ws + off;
        off += (bytes + 255) & ~(size_t)255;
        return p;
    };
    float* sq = (float*)alloc(B_ * N_ * 4);
    int* idx = (int*)alloc((size_t)B_ * N_ * K_ * 4);
    float* h1 = (float*)alloc((size_t)B_ * N_ * 64 * 4);
    float* h2 = (float*)alloc((size_t)B_ * N_ * 64 * 4);
    float* h3 = (float*)alloc((size_t)B_ * N_ * 128 * 4);
    float* h4 = (float*)alloc((size_t)B_ * N_ * 256 * 4);
    float* wd = (float*)alloc(3 * 64 * 4);
    float* wcd = (float*)alloc(3 * 64 * 4);
    float* b2 = (float*)alloc(512 * 4);
    float* f = (float*)alloc(B_ * 384 * 4);
    unsigned short* Wh = (unsigned short*)alloc((size_t)128 * 512 * 2);
    unsigned short* Wl = (unsigned short*)alloc((size_t)128 * 512 * 2);
    unsigned short* Hh = (unsigned short*)alloc((size_t)B_ * N_ * 128 * 2);
    unsigned short* Hl = (unsigned short*)alloc((size_t)B_ * N_ * 128 * 2);
    // dist (32 MB) and YZ (<=16 MB) have disjoint lifetimes within a layer: overlay.
    float* dist = (float*)alloc((size_t)B_ * N_ * N_ * 4);
    float* YZ = dist;
    (void)ws_size; (void)in_sizes; (void)n_in; (void)out_size;

    const int SELG = B_ * (N_ / 8);
    const int SG = (B_ * N_) / 256;
    const int DG = B_ * 64;
    const int GM = B_ * N_;  // points

    // ---- layer 1: 3 -> 64
    split_kernel<3, 32><<<SG, 256, 0, stream>>>(x, Hh, Hl, sq);
    distg_kernel<32><<<DG, 256, 0, stream>>>(Hh, Hl, sq, dist);
    sel_kernel<<<SELG, 256, 0, stream>>>(dist, idx);
    prep_kernel<3, 64><<<1, 256, 0, stream>>>(cw[0], cg[0], cb[0], cm[0], cv[0], wd, wcd, b2);
    y1z1_kernel<<<GM / 4, 256, 0, stream>>>(x, wd, wcd, b2, YZ);
    gathermax_kernel<64><<<GM / 4, 256, 0, stream>>>(YZ, idx, h1);

    // ---- layer 2: 64 -> 64
    split_kernel<64, 64><<<SG, 256, 0, stream>>>(h1, Hh, Hl, sq);
    distg_kernel<64><<<DG, 256, 0, stream>>>(Hh, Hl, sq, dist);
    sel_kernel<<<SELG, 256, 0, stream>>>(dist, idx);
    prep_mfma2<64, 64><<<(64 * 128 + 255) / 256, 256, 0, stream>>>(cw[1], cg[1], cb[1], cm[1], cv[1], Wh, Wl, b2);
    gemmYZ_kernel<64, 128><<<dim3(64, 1), 256, 0, stream>>>(Hh, Hl, Wh, Wl, b2, YZ);
    gathermax_kernel<64><<<GM / 4, 256, 0, stream>>>(YZ, idx, h2);

    // ---- layer 3: 64 -> 128
    split_kernel<64, 64><<<SG, 256, 0, stream>>>(h2, Hh, Hl, sq);
    distg_kernel<64><<<DG, 256, 0, stream>>>(Hh, Hl, sq, dist);
    sel_kernel<<<SELG, 256, 0, stream>>>(dist, idx);
    prep_mfma2<64, 128><<<(64 * 256 + 255) / 256, 256, 0, stream>>>(cw[2], cg[2], cb[2], cm[2], cv[2], Wh, Wl, b2);
    gemmYZ_kernel<64, 256><<<dim3(64, 2), 256, 0, stream>>>(Hh, Hl, Wh, Wl, b2, YZ);
    gathermax_kernel<128><<<GM / 2, 256, 0, stream>>>(YZ, idx, h3);

    // ---- layer 4: 128 -> 256
    split_kernel<128, 128><<<SG, 256, 0, stream>>>(h3, Hh, Hl, sq);
    distg_kernel<128><<<DG, 256, 0, stream>>>(Hh, Hl, sq, dist);
    sel_kernel<<<SELG, 256, 0, stream>>>(dist, idx);
    prep_mfma2<128, 256><<<(128 * 512 + 255) / 256, 256, 0, stream>>>(cw[3], cg[3], cb[3], cm[3], cv[3], Wh, Wl, b2);
    gemmYZ_kernel<128, 512><<<dim3(64, 4), 256, 0, stream>>>(Hh, Hl, Wh, Wl, b2, YZ);
    gathermax_kernel<256><<<GM, 256, 0, stream>>>(YZ, idx, h4);

    // ---- pooling + FC tail
    pool_kernel<128><<<B_ * 2, 256, 0, stream>>>(h3, f, 0);
    pool_kernel<256><<<B_ * 4, 256, 0, stream>>>(h4, f, 128);
    fc_tail<<<B_, 128, 0, stream>>>(f, f1w, f1b, n1g, n1b, n1m, n1v, f2w, f2b, n2g, n2b,
                                    n2m, n2v, f3w, f3b, out);
}